// Round 6
// baseline (3314.215 us; speedup 1.0000x reference)
//
#include <hip/hip_runtime.h>
#include <math.h>

// Problem constants
#define Bb 4
#define Ss 4096
#define Dd 1024
#define Hh 16
#define Ff 256
#define HDd 64
#define Mm (Bb*Ss)          // 16384 rows

typedef unsigned int u32;
typedef unsigned short u16;

// ---- bf16 helpers ----
__device__ __forceinline__ float bflo(u32 u){ union{u32 i; float f;} c; c.i = u << 16; return c.f; }
__device__ __forceinline__ float bfhi(u32 u){ union{u32 i; float f;} c; c.i = u & 0xffff0000u; return c.f; }
__device__ __forceinline__ float b2f(u16 u){ union{u32 i; float f;} c; c.i = ((u32)u) << 16; return c.f; }
__device__ __forceinline__ u16 f2b(float f){
  union{float f; u32 i;} c; c.f = f;
  u32 x = c.i;
  return (u16)((x + 0x7fffu + ((x >> 16) & 1u)) >> 16);   // RNE
}
__device__ __forceinline__ float softplusf(float x){
  return fmaxf(x, 0.f) + log1pf(expf(-fabsf(x)));   // jax.nn.softplus, stable
}

// ============================================================
// zero-fill (ws is re-poisoned 0xAA each call)
// ============================================================
__global__ void zero_f32(float* __restrict__ p, int n)
{
  int i = blockIdx.x * 256 + threadIdx.x;
  if (i < n) p[i] = 0.f;
}

// ============================================================
// GEMM: C[M,N] = A[M,K](f32) * W[N,K]^T(f32) + bias[N](f32)
// OT = u16 (bf16 store, our staging) or float (f32 store, final output).
// 128x128 tile, BK=16, 8x8/thread, fp32 VALU.
// Cross-verified bit-for-bit vs naive implementation (R3==R5 absmax).
// ============================================================
template<typename OT>
__global__ __launch_bounds__(256, 2) void gemm_bt(
    const float* __restrict__ A, const float* __restrict__ W,
    const float* __restrict__ bias, OT* __restrict__ C,
    int M, int N, int K)
{
  // +4 pad keeps float4 alignment (132*4=528B % 16 == 0) and breaks conflicts
  __shared__ __align__(16) float As[16][132];
  __shared__ __align__(16) float Bs[16][132];
  const int tid = threadIdx.x;
  const int tx = tid & 15, ty = tid >> 4;
  const int m0 = blockIdx.x * 128, n0 = blockIdx.y * 128;
  const int lr = tid >> 1;            // 0..127: tile row loaded by this thread
  const int lk = (tid & 1) << 3;      // 0 or 8: k-offset within chunk

  float acc[8][8];
#pragma unroll
  for (int i = 0; i < 8; i++)
#pragma unroll
    for (int j = 0; j < 8; j++) acc[i][j] = 0.f;

  for (int k0 = 0; k0 < K; k0 += 16) {
    const float* ap = A + (size_t)(m0 + lr) * K + k0 + lk;
    const float* wp = W + (size_t)(n0 + lr) * K + k0 + lk;
    float4 a0 = *reinterpret_cast<const float4*>(ap);
    float4 a1 = *reinterpret_cast<const float4*>(ap + 4);
    float4 b0 = *reinterpret_cast<const float4*>(wp);
    float4 b1 = *reinterpret_cast<const float4*>(wp + 4);
    As[lk + 0][lr] = a0.x; As[lk + 1][lr] = a0.y; As[lk + 2][lr] = a0.z; As[lk + 3][lr] = a0.w;
    As[lk + 4][lr] = a1.x; As[lk + 5][lr] = a1.y; As[lk + 6][lr] = a1.z; As[lk + 7][lr] = a1.w;
    Bs[lk + 0][lr] = b0.x; Bs[lk + 1][lr] = b0.y; Bs[lk + 2][lr] = b0.z; Bs[lk + 3][lr] = b0.w;
    Bs[lk + 4][lr] = b1.x; Bs[lk + 5][lr] = b1.y; Bs[lk + 6][lr] = b1.z; Bs[lk + 7][lr] = b1.w;
    __syncthreads();
#pragma unroll
    for (int kk = 0; kk < 16; kk++) {
      float a[8], b[8];
      *reinterpret_cast<float4*>(&a[0]) = *reinterpret_cast<const float4*>(&As[kk][ty * 8]);
      *reinterpret_cast<float4*>(&a[4]) = *reinterpret_cast<const float4*>(&As[kk][ty * 8 + 4]);
      *reinterpret_cast<float4*>(&b[0]) = *reinterpret_cast<const float4*>(&Bs[kk][tx * 8]);
      *reinterpret_cast<float4*>(&b[4]) = *reinterpret_cast<const float4*>(&Bs[kk][tx * 8 + 4]);
#pragma unroll
      for (int i = 0; i < 8; i++)
#pragma unroll
        for (int j = 0; j < 8; j++) acc[i][j] += a[i] * b[j];
    }
    __syncthreads();
  }

  float bvv[8];
#pragma unroll
  for (int j = 0; j < 8; j++) bvv[j] = bias[n0 + tx * 8 + j];

#pragma unroll
  for (int i = 0; i < 8; i++) {
    if constexpr (sizeof(OT) == 2) {
      u32 w[4];
#pragma unroll
      for (int j = 0; j < 4; j++) {
        u16 lo = f2b(acc[i][2 * j]     + bvv[2 * j]);
        u16 hi = f2b(acc[i][2 * j + 1] + bvv[2 * j + 1]);
        w[j] = (u32)lo | ((u32)hi << 16);
      }
      *reinterpret_cast<uint4*>((u16*)C + (size_t)(m0 + ty * 8 + i) * N + n0 + tx * 8) =
          make_uint4(w[0], w[1], w[2], w[3]);
    } else {
      float* cp = (float*)C + (size_t)(m0 + ty * 8 + i) * N + n0 + tx * 8;
      *reinterpret_cast<float4*>(cp) =
          make_float4(acc[i][0] + bvv[0], acc[i][1] + bvv[1], acc[i][2] + bvv[2], acc[i][3] + bvv[3]);
      *reinterpret_cast<float4*>(cp + 4) =
          make_float4(acc[i][4] + bvv[4], acc[i][5] + bvv[5], acc[i][6] + bvv[6], acc[i][7] + bvv[7]);
    }
  }
}

// ============================================================
// rf [H][HD][F] f32 -> rft [H][F][HD] f32 (contiguous wave-uniform rows)
// ============================================================
__global__ void rf_transpose(const float* __restrict__ rf, float* __restrict__ rft)
{
  const int h = blockIdx.x, d = blockIdx.y, f = threadIdx.x;
  rft[((size_t)h * Ff + f) * HDd + d] = rf[((size_t)(h * HDd + d)) * Ff + f];
}

// ============================================================
// kv[bh][f][d] += sum_s softplus(k[s,:]·rf[:,f]) * v[s,d]; ksum[bh][f].
// thread = f (rf column in VGPRs); k/v rows wave-uniform -> scalar loads.
// ============================================================
#define SCH 512
__global__ __launch_bounds__(256, 2) void kv_ksum_kernel(
    const u16* __restrict__ Km, const u16* __restrict__ Vm,
    const float* __restrict__ rf, float* __restrict__ kv, float* __restrict__ ksum)
{
  const int bh = blockIdx.x;
  const int b = bh >> 4, h = bh & 15;
  const int f = threadIdx.x;
  const int s0 = blockIdx.y * SCH;

  float rfc[64];
#pragma unroll
  for (int d = 0; d < 64; d++) rfc[d] = rf[((size_t)(h * 64 + d)) * Ff + f];  // coalesced f32

  float kva[64];
#pragma unroll
  for (int d = 0; d < 64; d++) kva[d] = 0.f;
  float ks = 0.f;

  for (int s = 0; s < SCH; s++) {
    const size_t base = (size_t)(b * Ss + s0 + s) * Dd + h * 64;   // wave-uniform
    const u32* kr = reinterpret_cast<const u32*>(Km + base);
    const u32* vr = reinterpret_cast<const u32*>(Vm + base);
    float p0 = 0.f, p1 = 0.f, p2 = 0.f, p3 = 0.f;
#pragma unroll
    for (int t = 0; t < 8; t++) {
      u32 ua = kr[4 * t], ub = kr[4 * t + 1], uc = kr[4 * t + 2], ud = kr[4 * t + 3];
      p0 += bflo(ua) * rfc[8 * t]     + bfhi(ua) * rfc[8 * t + 1];
      p1 += bflo(ub) * rfc[8 * t + 2] + bfhi(ub) * rfc[8 * t + 3];
      p2 += bflo(uc) * rfc[8 * t + 4] + bfhi(uc) * rfc[8 * t + 5];
      p3 += bflo(ud) * rfc[8 * t + 6] + bfhi(ud) * rfc[8 * t + 7];
    }
    float kp = softplusf((p0 + p1) + (p2 + p3));
    ks += kp;
#pragma unroll
    for (int t = 0; t < 32; t++) {
      u32 u = vr[t];
      kva[2 * t]     += kp * bflo(u);
      kva[2 * t + 1] += kp * bfhi(u);
    }
  }

  float* kvp = kv + ((size_t)bh * Ff + f) * HDd;
#pragma unroll
  for (int d = 0; d < 64; d++) atomicAdd(kvp + d, kva[d]);
  atomicAdd(ksum + (size_t)bh * Ff + f, ks);
}

// ============================================================
// attn[s, h*64+d] = (sum_f softplus(q·rf_f) * kv[f,d]) / (sum_f qp*ksum[f] + 1e-8)
// attn (fp32) aliases the dead k|v region.
// ============================================================
__global__ __launch_bounds__(256, 2) void attn_kernel(
    const u16* __restrict__ Qm, const float* __restrict__ rft,
    const float* __restrict__ kv, const float* __restrict__ ksum,
    float* __restrict__ attn)
{
  const int bh = blockIdx.x;
  const int b = bh >> 4, h = bh & 15;
  const int s = blockIdx.y * 256 + threadIdx.x;

  const u32* qr = reinterpret_cast<const u32*>(Qm + (size_t)(b * Ss + s) * Dd + h * 64);
  float q[64];
#pragma unroll
  for (int i = 0; i < 32; i++) { u32 u = qr[i]; q[2 * i] = bflo(u); q[2 * i + 1] = bfhi(u); }

  float acc[64];
#pragma unroll
  for (int d = 0; d < 64; d++) acc[d] = 0.f;
  float den = 0.f;

  const float* rfh = rft + (size_t)h * Ff * HDd;
  const float* kvh = kv + (size_t)bh * Ff * HDd;
  const float* ksh = ksum + (size_t)bh * Ff;

  for (int f = 0; f < Ff; f++) {
    const float* rc = rfh + f * HDd;   // wave-uniform
    float p0 = 0.f, p1 = 0.f, p2 = 0.f, p3 = 0.f;
#pragma unroll
    for (int d = 0; d < 64; d += 4) {
      p0 += q[d] * rc[d];         p1 += q[d + 1] * rc[d + 1];
      p2 += q[d + 2] * rc[d + 2]; p3 += q[d + 3] * rc[d + 3];
    }
    float qp = softplusf((p0 + p1) + (p2 + p3));
    den += qp * ksh[f];
    const float* kc = kvh + f * HDd;   // wave-uniform
#pragma unroll
    for (int d = 0; d < 64; d++) acc[d] += qp * kc[d];
  }

  float inv = 1.f / (den + 1e-8f);
  float* op = attn + (size_t)(b * Ss + s) * Dd + h * 64;
#pragma unroll
  for (int d = 0; d < 64; d += 4)
    *reinterpret_cast<float4*>(op + d) =
        make_float4(acc[d] * inv, acc[d + 1] * inv, acc[d + 2] * inv, acc[d + 3] * inv);
}

// ============================================================
extern "C" void kernel_launch(void* const* d_in, const int* in_sizes, int n_in,
                              void* d_out, int out_size, void* d_ws, size_t ws_size,
                              hipStream_t stream)
{
  // Inputs f32 (reference dtypes); OUTPUT f32 (reference output dtype).
  const float* x  = (const float*)d_in[0];
  const float* Wq = (const float*)d_in[1];
  const float* bq = (const float*)d_in[2];
  const float* Wk = (const float*)d_in[3];
  const float* bk = (const float*)d_in[4];
  const float* Wv = (const float*)d_in[5];
  const float* bv = (const float*)d_in[6];
  const float* Wo = (const float*)d_in[7];
  const float* bo = (const float*)d_in[8];
  const float* rf = (const float*)d_in[9];

  // workspace layout (~106 MB total; attn fp32 ALIASES the dead k|v region)
  char* w = (char*)d_ws;
  u16* q = (u16*)w;        w += (size_t)Mm * Dd * 2;               // 33.5 MB
  u16* k = (u16*)w;                                                 // k at +33.5 MB
  float* attn = (float*)w; w += (size_t)Mm * Dd * 2;               // attn spans k|v (67.1 MB fp32)
  u16* v = (u16*)w;        w += (size_t)Mm * Dd * 2;               // v at +67.1 MB
  float* kv = (float*)w;   w += (size_t)(Bb * Hh) * Ff * HDd * 4;  // 4.19 MB
  float* ks = (float*)w;   w += (size_t)(Bb * Hh) * Ff * 4;        // 64 KB
  float* rft = (float*)w;  w += (size_t)Hh * Ff * HDd * 4;         // 1.05 MB

  // kv|ksum accumulated via atomics -> zero them (ws is re-poisoned each call)
  const int nz = (Bb * Hh) * Ff * HDd + (Bb * Hh) * Ff;
  zero_f32<<<(nz + 255) / 256, 256, 0, stream>>>(kv, nz);
  rf_transpose<<<dim3(Hh, HDd), 256, 0, stream>>>(rf, rft);

  dim3 gg(Mm / 128, Dd / 128);
  gemm_bt<u16><<<gg, 256, 0, stream>>>(x, Wq, bq, q, Mm, Dd, Dd);
  gemm_bt<u16><<<gg, 256, 0, stream>>>(x, Wk, bk, k, Mm, Dd, Dd);
  gemm_bt<u16><<<gg, 256, 0, stream>>>(x, Wv, bv, v, Mm, Dd, Dd);

  kv_ksum_kernel<<<dim3(Bb * Hh, Ss / SCH), 256, 0, stream>>>(k, v, rf, kv, ks);
  attn_kernel<<<dim3(Bb * Hh, Ss / 256), 256, 0, stream>>>(q, rft, kv, ks, attn);

  // Final projection: f32 output per reference dtype
  gemm_bt<float><<<gg, 256, 0, stream>>>(attn, Wo, bo, (float*)d_out, Mm, Dd, Dd);
}

// Round 7
// 2354.716 us; speedup vs baseline: 1.4075x; 1.4075x over previous
//
#include <hip/hip_runtime.h>
#include <math.h>

// Problem constants
#define Bb 4
#define Ss 4096
#define Dd 1024
#define Hh 16
#define Ff 256
#define HDd 64
#define Mm (Bb*Ss)          // 16384 rows

typedef unsigned int u32;
typedef unsigned short u16;

typedef __attribute__((ext_vector_type(8))) short bf16x8;   // 8 bf16 = 4 VGPRs (per guide §3)
typedef __attribute__((ext_vector_type(4))) float f32x4;

// ---- bf16 helpers ----
__device__ __forceinline__ float bflo(u32 u){ union{u32 i; float f;} c; c.i = u << 16; return c.f; }
__device__ __forceinline__ float bfhi(u32 u){ union{u32 i; float f;} c; c.i = u & 0xffff0000u; return c.f; }
__device__ __forceinline__ u16 f2b(float f){
  union{float f; u32 i;} c; c.f = f;
  u32 x = c.i;
  return (u16)((x + 0x7fffu + ((x >> 16) & 1u)) >> 16);   // RNE
}
__device__ __forceinline__ float softplusf(float x){
  return fmaxf(x, 0.f) + log1pf(expf(-fabsf(x)));   // jax.nn.softplus, stable
}

// ============================================================
// f32 -> bf16 elementwise (8 elems/thread, vectorized)
// ============================================================
__global__ void cvt_bf16(const float* __restrict__ in, u16* __restrict__ out, int n)
{
  int i = (blockIdx.x * 256 + threadIdx.x) * 8;
  if (i >= n) return;
  float4 a = *reinterpret_cast<const float4*>(in + i);
  float4 b = *reinterpret_cast<const float4*>(in + i + 4);
  u32 w0 = (u32)f2b(a.x) | ((u32)f2b(a.y) << 16);
  u32 w1 = (u32)f2b(a.z) | ((u32)f2b(a.w) << 16);
  u32 w2 = (u32)f2b(b.x) | ((u32)f2b(b.y) << 16);
  u32 w3 = (u32)f2b(b.z) | ((u32)f2b(b.w) << 16);
  *reinterpret_cast<uint4*>(out + i) = make_uint4(w0, w1, w2, w3);
}

// ============================================================
// zero-fill (ws is re-poisoned 0xAA each call)
// ============================================================
__global__ void zero_f32(float* __restrict__ p, int n)
{
  int i = blockIdx.x * 256 + threadIdx.x;
  if (i < n) p[i] = 0.f;
}

// ============================================================
// MFMA GEMM: C[M,N] = A[M,K](bf16) * W[N,K]^T(bf16) + bias[N](f32)
// OT = u16 (bf16 store) or float (f32 store, final output).
// 128x128 tile, BK=32, 4 waves (2x2 of 64x64), 16 mfma_16x16x32_bf16/wave/K-step.
// Verified layouts (m89/m91/m120): A[m=lane&15][k=quad*8+j],
// B[k=quad*8+j][n=lane&15], D[row=quad*4+r][col=lane&15].
// ============================================================
template<typename OT>
__global__ __launch_bounds__(256, 2) void mfma_gemm_bt(
    const u16* __restrict__ A, const u16* __restrict__ W,
    const float* __restrict__ bias, OT* __restrict__ C,
    int M, int N, int K)
{
  // rows of 32 bf16 + 8 pad = 40 u16 (80 B): frag-read banks 20r+4q mod 32 -> 2-way (free)
  __shared__ __align__(16) u16 As[128 * 40];
  __shared__ __align__(16) u16 Bs[128 * 40];

  const int tid = threadIdx.x;
  const int wave = tid >> 6, lane = tid & 63;
  const int quad = lane >> 4, lm = lane & 15;
  const int wm = (wave >> 1) * 64, wn = (wave & 1) * 64;
  const int m0 = blockIdx.x * 128, n0 = blockIdx.y * 128;

  f32x4 acc[4][4] = {};   // zero-init

  for (int k0 = 0; k0 < K; k0 += 32) {
#pragma unroll
    for (int i = 0; i < 2; i++) {
      int slot = tid + 256 * i;          // 512 slots: 128 rows x 4 col-groups
      int r = slot >> 2, cg = slot & 3;
      *reinterpret_cast<uint4*>(&As[r * 40 + cg * 8]) =
          *reinterpret_cast<const uint4*>(A + (size_t)(m0 + r) * K + k0 + cg * 8);
      *reinterpret_cast<uint4*>(&Bs[r * 40 + cg * 8]) =
          *reinterpret_cast<const uint4*>(W + (size_t)(n0 + r) * K + k0 + cg * 8);
    }
    __syncthreads();

    bf16x8 af[4], bf[4];
#pragma unroll
    for (int mi = 0; mi < 4; mi++)
      af[mi] = *reinterpret_cast<const bf16x8*>(&As[(wm + mi * 16 + lm) * 40 + quad * 8]);
#pragma unroll
    for (int ni = 0; ni < 4; ni++)
      bf[ni] = *reinterpret_cast<const bf16x8*>(&Bs[(wn + ni * 16 + lm) * 40 + quad * 8]);
#pragma unroll
    for (int mi = 0; mi < 4; mi++)
#pragma unroll
      for (int ni = 0; ni < 4; ni++)
        acc[mi][ni] = __builtin_amdgcn_mfma_f32_16x16x32_bf16(af[mi], bf[ni], acc[mi][ni], 0, 0, 0);
    __syncthreads();
  }

  // epilogue: lane l, reg r -> C[m0+wm+mi*16+quad*4+r][n0+wn+ni*16+lm]
#pragma unroll
  for (int mi = 0; mi < 4; mi++)
#pragma unroll
    for (int ni = 0; ni < 4; ni++) {
      const int n = n0 + wn + ni * 16 + lm;
      const float bv = bias[n];
#pragma unroll
      for (int r = 0; r < 4; r++) {
        const int m = m0 + wm + mi * 16 + quad * 4 + r;
        const float val = acc[mi][ni][r] + bv;
        if constexpr (sizeof(OT) == 2) ((u16*)C)[(size_t)m * N + n] = f2b(val);
        else                           ((float*)C)[(size_t)m * N + n] = val;
      }
    }
}

// ============================================================
// rf [H][HD][F] f32 -> rft [H][F][HD] f32 (contiguous wave-uniform rows)
// ============================================================
__global__ void rf_transpose(const float* __restrict__ rf, float* __restrict__ rft)
{
  const int h = blockIdx.x, d = blockIdx.y, f = threadIdx.x;
  rft[((size_t)h * Ff + f) * HDd + d] = rf[((size_t)(h * HDd + d)) * Ff + f];
}

// ============================================================
// kv v2: thread = (fi, d-quarter). 16 acc + 16 rf regs -> no spill.
// Dot over 64 = 4-lane partials + shfl_xor(1,2). Grid (64,4,NS).
// ============================================================
#define NS 4
#define SCH2 (Ss / NS)
__global__ __launch_bounds__(256) void kv_ksum_v2(
    const u16* __restrict__ Km, const u16* __restrict__ Vm,
    const float* __restrict__ rf, float* __restrict__ kv, float* __restrict__ ksum)
{
  const int bh = blockIdx.x;
  const int b = bh >> 4, h = bh & 15;
  const int ft = blockIdx.y;                 // f-tile of 64
  const int s0 = blockIdx.z * SCH2;
  const int t = threadIdx.x;
  const int fi = t >> 2, dg = t & 3;         // f index, d-quarter
  const int f = ft * 64 + fi;

  float rfp[16];                             // rf[h][dg*16+i][f]
#pragma unroll
  for (int i = 0; i < 16; i++)
    rfp[i] = rf[((size_t)(h * HDd + dg * 16 + i)) * Ff + f];

  float acc[16];
#pragma unroll
  for (int i = 0; i < 16; i++) acc[i] = 0.f;
  float ks = 0.f;

  for (int s = s0; s < s0 + SCH2; s++) {
    const size_t base = ((size_t)(b * Ss + s)) * Dd + h * HDd + dg * 16;
    const u32* kr = reinterpret_cast<const u32*>(Km + base);
    float p = 0.f;
#pragma unroll
    for (int j = 0; j < 8; j++) {
      u32 u = kr[j];
      p += bflo(u) * rfp[2 * j] + bfhi(u) * rfp[2 * j + 1];
    }
    p += __shfl_xor(p, 1, 64);
    p += __shfl_xor(p, 2, 64);               // all 4 lanes of the group now hold full dot
    const float kp = softplusf(p);
    if (dg == 0) ks += kp;
    const u32* vr = reinterpret_cast<const u32*>(Vm + base);
#pragma unroll
    for (int j = 0; j < 8; j++) {
      u32 u = vr[j];
      acc[2 * j]     += kp * bflo(u);
      acc[2 * j + 1] += kp * bfhi(u);
    }
  }

  float* kvp = kv + ((size_t)bh * Ff + f) * HDd + dg * 16;
#pragma unroll
  for (int i = 0; i < 16; i++) atomicAdd(kvp + i, acc[i]);
  if (dg == 0) atomicAdd(ksum + (size_t)bh * Ff + f, ks);
}

// ============================================================
// attn[s][h*64+d] bf16 = (sum_f softplus(q·rf_f) * kv[f,d]) / (qp·ksum + 1e-8)
// Writes bf16 (feeds final MFMA GEMM); aliases dead xb region.
// ============================================================
__global__ __launch_bounds__(256, 2) void attn_kernel(
    const u16* __restrict__ Qm, const float* __restrict__ rft,
    const float* __restrict__ kv, const float* __restrict__ ksum,
    u16* __restrict__ attnb)
{
  const int bh = blockIdx.x;
  const int b = bh >> 4, h = bh & 15;
  const int s = blockIdx.y * 256 + threadIdx.x;

  const size_t base = (size_t)(b * Ss + s) * Dd + h * 64;
  const u32* qr = reinterpret_cast<const u32*>(Qm + base);
  float q[64];
#pragma unroll
  for (int i = 0; i < 32; i++) { u32 u = qr[i]; q[2 * i] = bflo(u); q[2 * i + 1] = bfhi(u); }

  float acc[64];
#pragma unroll
  for (int d = 0; d < 64; d++) acc[d] = 0.f;
  float den = 0.f;

  const float* rfh = rft + (size_t)h * Ff * HDd;
  const float* kvh = kv + (size_t)bh * Ff * HDd;
  const float* ksh = ksum + (size_t)bh * Ff;

  for (int fc = 0; fc < Ff; fc++) {
    const float* rc = rfh + fc * HDd;   // wave-uniform
    float p0 = 0.f, p1 = 0.f, p2 = 0.f, p3 = 0.f;
#pragma unroll
    for (int d = 0; d < 64; d += 4) {
      p0 += q[d] * rc[d];         p1 += q[d + 1] * rc[d + 1];
      p2 += q[d + 2] * rc[d + 2]; p3 += q[d + 3] * rc[d + 3];
    }
    float qp = softplusf((p0 + p1) + (p2 + p3));
    den += qp * ksh[fc];
    const float* kc = kvh + fc * HDd;   // wave-uniform
#pragma unroll
    for (int d = 0; d < 64; d++) acc[d] += qp * kc[d];
  }

  const float inv = 1.f / (den + 1e-8f);
  u32* op = reinterpret_cast<u32*>(attnb + base);
#pragma unroll
  for (int i = 0; i < 32; i++)
    op[i] = (u32)f2b(acc[2 * i] * inv) | ((u32)f2b(acc[2 * i + 1] * inv) << 16);
}

// ============================================================
extern "C" void kernel_launch(void* const* d_in, const int* in_sizes, int n_in,
                              void* d_out, int out_size, void* d_ws, size_t ws_size,
                              hipStream_t stream)
{
  const float* x  = (const float*)d_in[0];
  const float* Wq = (const float*)d_in[1];
  const float* bq = (const float*)d_in[2];
  const float* Wk = (const float*)d_in[3];
  const float* bk = (const float*)d_in[4];
  const float* Wv = (const float*)d_in[5];
  const float* bv = (const float*)d_in[6];
  const float* Wo = (const float*)d_in[7];
  const float* bo = (const float*)d_in[8];
  const float* rf = (const float*)d_in[9];

  // workspace (~147 MB). attn-bf16 ALIASES xb (dead after the V GEMM).
  char* w = (char*)d_ws;
  u16* xb = (u16*)w;        w += (size_t)Mm * Dd * 2;               // 33.5 MB (also attn-bf16)
  u16* q  = (u16*)w;        w += (size_t)Mm * Dd * 2;               // 33.5 MB
  u16* k  = (u16*)w;        w += (size_t)Mm * Dd * 2;               // 33.5 MB
  u16* v  = (u16*)w;        w += (size_t)Mm * Dd * 2;               // 33.5 MB
  u16* wqb = (u16*)w;       w += (size_t)Dd * Dd * 2;               // 2 MB
  u16* wkb = (u16*)w;       w += (size_t)Dd * Dd * 2;
  u16* wvb = (u16*)w;       w += (size_t)Dd * Dd * 2;
  u16* wob = (u16*)w;       w += (size_t)Dd * Dd * 2;
  float* kv = (float*)w;    w += (size_t)(Bb * Hh) * Ff * HDd * 4;  // 4.19 MB
  float* ks = (float*)w;    w += (size_t)(Bb * Hh) * Ff * 4;        // 64 KB
  float* rft = (float*)w;   w += (size_t)Hh * Ff * HDd * 4;         // 1.05 MB

  // f32 -> bf16 conversions
  cvt_bf16<<<(Mm * Dd / 8 + 255) / 256, 256, 0, stream>>>(x, xb, Mm * Dd);
  cvt_bf16<<<(Dd * Dd / 8 + 255) / 256, 256, 0, stream>>>(Wq, wqb, Dd * Dd);
  cvt_bf16<<<(Dd * Dd / 8 + 255) / 256, 256, 0, stream>>>(Wk, wkb, Dd * Dd);
  cvt_bf16<<<(Dd * Dd / 8 + 255) / 256, 256, 0, stream>>>(Wv, wvb, Dd * Dd);
  cvt_bf16<<<(Dd * Dd / 8 + 255) / 256, 256, 0, stream>>>(Wo, wob, Dd * Dd);

  const int nz = (Bb * Hh) * Ff * HDd + (Bb * Hh) * Ff;
  zero_f32<<<(nz + 255) / 256, 256, 0, stream>>>(kv, nz);
  rf_transpose<<<dim3(Hh, HDd), 256, 0, stream>>>(rf, rft);

  const dim3 gg(Mm / 128, Dd / 128);
  mfma_gemm_bt<u16><<<gg, 256, 0, stream>>>(xb, wqb, bq, q, Mm, Dd, Dd);
  mfma_gemm_bt<u16><<<gg, 256, 0, stream>>>(xb, wkb, bk, k, Mm, Dd, Dd);
  mfma_gemm_bt<u16><<<gg, 256, 0, stream>>>(xb, wvb, bv, v, Mm, Dd, Dd);

  kv_ksum_v2<<<dim3(Bb * Hh, Ff / 64, NS), 256, 0, stream>>>(k, v, rf, kv, ks);
  attn_kernel<<<dim3(Bb * Hh, Ss / 256), 256, 0, stream>>>(q, rft, kv, ks, xb);

  // final projection: f32 output
  mfma_gemm_bt<float><<<gg, 256, 0, stream>>>(xb, wob, bo, (float*)d_out, Mm, Dd, Dd);
}